// Round 10
// baseline (240.643 us; speedup 1.0000x reference)
//
#include <hip/hip_runtime.h>

typedef float f32x4 __attribute__((ext_vector_type(4)));
typedef float f32x16 __attribute__((ext_vector_type(16)));
typedef __bf16 bf16x8 __attribute__((ext_vector_type(8)));
typedef unsigned short u16x8 __attribute__((ext_vector_type(8)));
typedef unsigned int u32x4 __attribute__((ext_vector_type(4)));

#define SCQ 0.1803368801111183f  // 0.125 * log2(e): softmax in exp2 domain

__device__ inline unsigned short f2bf(float f) {
  unsigned int u = __builtin_bit_cast(unsigned int, f);
  u += 0x7FFFu + ((u >> 16) & 1u);
  return (unsigned short)(u >> 16);
}

__device__ inline float fexp2(float x) {
#if __has_builtin(__builtin_amdgcn_exp2f)
  return __builtin_amdgcn_exp2f(x);
#else
  return exp2f(x);
#endif
}

// pack two f32 -> one dword of 2 bf16 (lo = a, hi = b), RNE
__device__ inline unsigned int cvtpk_bf16(float a, float b) {
  unsigned int r;
  __asm__("v_cvt_pk_bf16_f32 %0, %1, %2" : "=v"(r) : "v"(a), "v"(b));
  return r;
}
// swap a's upper 32 lanes with b's lower 32 lanes (both modified)
__device__ inline void permswap32(unsigned int& a, unsigned int& b) {
  __asm__("v_permlane32_swap_b32 %0, %1" : "+v"(a), "+v"(b));
}

__device__ inline void gload_lds16(const unsigned short* g, unsigned short* l) {
  __builtin_amdgcn_global_load_lds(
      (const __attribute__((address_space(1))) unsigned int*)g,
      (__attribute__((address_space(3))) unsigned int*)l, 16, 0, 0);
}

// ---------------- fp32 -> bf16 conversion (x + 4 weight matrices, one launch) ----
__global__ void cvt_all(const float* __restrict__ x,
                        const float* __restrict__ wq, const float* __restrict__ wk,
                        const float* __restrict__ wv, const float* __restrict__ wp,
                        unsigned short* __restrict__ xb,
                        unsigned short* __restrict__ oq, unsigned short* __restrict__ ok,
                        unsigned short* __restrict__ ov, unsigned short* __restrict__ op_) {
  int gid = blockIdx.x;
  const float* src;
  unsigned short* dst;
  int i;
  if (gid < 8192) {
    src = x; dst = xb;
    i = (gid * 256 + threadIdx.x) * 4;
  } else {
    int g = gid - 8192;
    int m = g >> 10;
    src = (m == 0) ? wq : (m == 1) ? wk : (m == 2) ? wv : wp;
    dst = (m == 0) ? oq : (m == 1) ? ok : (m == 2) ? ov : op_;
    i = ((g & 1023) * 256 + threadIdx.x) * 4;
  }
  float4 f = *(const float4*)(src + i);
  ushort4 o;
  o.x = f2bf(f.x); o.y = f2bf(f.y); o.z = f2bf(f.z); o.w = f2bf(f.w);
  *(ushort4*)(dst + i) = o;
}

// ---------------- GEMM 128x128 (m97 structure), fused V-transpose epilogue ----------
// out[m][n] = sum_k A[m][k]*Bt[n][k] + bias[n]. 256 thr = 4 waves, 64x64/wave,
// 2x2 of 32x32x16 MFMA, BK=64, global_load_lds w16, chunk-XOR swizzle.
// MODE 0 (fused QKV, N=3072): which=col>>10 -> {Q,K,V}.
//   Q: pre-scaled by SCQ, bf16 scatter [B,H,T,D] into out; K same (no scale).
//   V (n0>=2048, block-uniform): accumulators routed through the dead 32 KB
//   staging LDS as an XOR-swizzled [d][t] tile, then stored TRANSPOSED to
//   vt[bh][d][t] with coalesced 256-B segments.
// MODE 1: fp32 row-major MxN with bias b0.
template <int MODE>
__global__ __launch_bounds__(256) void gemm128(const unsigned short* __restrict__ A,
                                               const unsigned short* __restrict__ Bt,
                                               const float* __restrict__ b0,
                                               const float* __restrict__ b1,
                                               const float* __restrict__ b2,
                                               void* __restrict__ out,
                                               unsigned short* __restrict__ vt,
                                               int M, int N, int K) {
  __shared__ __align__(16) unsigned short Sh[2][128 * 64];
  unsigned short* As = Sh[0];
  unsigned short* Bs = Sh[1];
  const int tid = threadIdx.x;
  const int lane = tid & 63, w = tid >> 6;
  const int l31 = lane & 31, half = lane >> 5;
  const int wm = w & 1, wn = w >> 1;
  const int m0 = blockIdx.x * 128, n0 = blockIdx.y * 128;

  f32x16 acc[2][2] = {};

  for (int kb = 0; kb < K; kb += 64) {
#pragma unroll
    for (int j = 0; j < 4; j++) {
      int ch = j * 256 + w * 64 + lane;
      int row = ch >> 3, pc = ch & 7;
      int c = pc ^ (row & 7);
      gload_lds16(A + (size_t)(m0 + row) * K + kb + c * 8, As + (size_t)(j * 256 + w * 64) * 8);
      gload_lds16(Bt + (size_t)(n0 + row) * K + kb + c * 8, Bs + (size_t)(j * 256 + w * 64) * 8);
    }
    __syncthreads();
#pragma unroll
    for (int ks = 0; ks < 64; ks += 16) {
      bf16x8 af[2], bfr[2];
#pragma unroll
      for (int at = 0; at < 2; at++) {
        int row = wm * 64 + at * 32 + l31;
        int pc = ((ks >> 3) + half) ^ (row & 7);
        af[at] = *(const bf16x8*)(As + row * 64 + pc * 8);
      }
#pragma unroll
      for (int nt = 0; nt < 2; nt++) {
        int row = wn * 64 + nt * 32 + l31;
        int pc = ((ks >> 3) + half) ^ (row & 7);
        bfr[nt] = *(const bf16x8*)(Bs + row * 64 + pc * 8);
      }
#pragma unroll
      for (int at = 0; at < 2; at++)
#pragma unroll
        for (int nt = 0; nt < 2; nt++)
          acc[at][nt] = __builtin_amdgcn_mfma_f32_32x32x16_bf16(af[at], bfr[nt], acc[at][nt], 0, 0, 0);
    }
    __syncthreads();
  }

  if (MODE == 0 && n0 >= 2048) {
    // ---- V: LDS transpose + coalesced Vt store ----
    unsigned short* Lt = &Sh[0][0];  // 128 x 128 u16 = 32 KB (staging LDS, dead)
#pragma unroll
    for (int at = 0; at < 2; at++)
#pragma unroll
      for (int nt = 0; nt < 2; nt++) {
        int d = wn * 64 + nt * 32 + l31;          // d_local in [0,128)
        float bv = b2[(n0 & 1023) + d];
        int swz = (d & 31) << 2;                  // bank-spread XOR, bijective in t
#pragma unroll
        for (int reg = 0; reg < 16; reg++) {
          int t = wm * 64 + at * 32 + (reg & 3) + 8 * (reg >> 2) + 4 * half;
          Lt[d * 128 + (t ^ swz)] = f2bf(acc[at][nt][reg] + bv);
        }
      }
    __syncthreads();
    const int bb = m0 >> 11, t0 = m0 & 2047;
#pragma unroll
    for (int i = 0; i < 16; i++) {
      int d = (tid >> 5) + i * 8;
      int tb = (tid & 31) * 4;
      ushort4 val = *(const ushort4*)&Lt[d * 128 + (tb ^ ((d & 31) << 2))];
      int h = ((n0 & 1023) + d) >> 6;
      *(ushort4*)(vt + ((size_t)((bb * 16 + h) * 64 + (d & 63))) * 2048 + t0 + tb) = val;
    }
    return;
  }

#pragma unroll
  for (int at = 0; at < 2; at++)
#pragma unroll
    for (int nt = 0; nt < 2; nt++) {
      int col = n0 + wn * 64 + nt * 32 + l31;
      float bv, sc;
      int which = 0, cl = col;
      if (MODE == 0) {
        which = col >> 10; cl = col & 1023;
        const float* bp = (which == 0) ? b0 : b1;
        bv = bp[cl];
        sc = (which == 0) ? SCQ : 1.f;
      } else {
        bv = b0[col]; sc = 1.f;
      }
#pragma unroll
      for (int reg = 0; reg < 16; reg++) {
        int row = m0 + wm * 64 + at * 32 + (reg & 3) + 8 * (reg >> 2) + 4 * half;
        float v = (acc[at][nt][reg] + bv) * sc;
        if (MODE == 0) {
          int h = cl >> 6, d = cl & 63;
          int b = row >> 11, t = row & 2047;
          ((unsigned short*)out)[(size_t)which * 8388608 +
                                 ((size_t)((b * 16 + h) * 2048 + t)) * 64 + d] = f2bf(v);
        } else {
          ((float*)out)[(size_t)row * N + col] = v;
        }
      }
    }
}

// ---------------- GEMM 128x256, counted-vmcnt schedule (proj) ----------------
__global__ __launch_bounds__(512, 2) void gemm8p(const unsigned short* __restrict__ A,
                                                 const unsigned short* __restrict__ Bt,
                                                 const float* __restrict__ b0,
                                                 void* __restrict__ out,
                                                 int M, int N, int K) {
  __shared__ __align__(16) unsigned short Lg[2][3][128 * 64];
  const int tid = threadIdx.x;
  const int lane = tid & 63, w = tid >> 6;
  const int qm = w >> 2, qn = w & 3;       // wave position: 2M x 4N
  const int l15 = lane & 15, kq = lane >> 4;
  const int m0 = blockIdx.x * 128, n0 = blockIdx.y * 256;
  const int NT = K >> 6;

  const int row0 = tid >> 3, c0 = (tid & 7) ^ (row0 & 7);
  const int row1 = row0 + 64, c1 = (tid & 7) ^ (row1 & 7);

  auto stage = [&](int tt, int h) {
    if (tt < NT) {
      const unsigned short* s_ = (h == 0) ? A : Bt;
      const int rbase = (h == 0) ? m0 : (h == 1 ? n0 : n0 + 128);
      unsigned short* d = &Lg[tt & 1][h][0];
      gload_lds16(s_ + (size_t)(rbase + row0) * K + tt * 64 + c0 * 8, d + (size_t)tid * 8);
      gload_lds16(s_ + (size_t)(rbase + row1) * K + tt * 64 + c1 * 8, d + (size_t)(tid + 512) * 8);
    }
  };

  auto rdA = [&](const unsigned short* R, u16x8 (&a)[4][2]) {
#pragma unroll
    for (int mf = 0; mf < 4; mf++) {
      int row = qm * 64 + mf * 16 + l15;
#pragma unroll
      for (int kf = 0; kf < 2; kf++) {
        int pc = (kf * 4 + kq) ^ (row & 7);
        a[mf][kf] = *(const u16x8*)(R + row * 64 + pc * 8);
      }
    }
  };
  auto rdB = [&](const unsigned short* R, u16x8 (&bb)[2][2]) {
#pragma unroll
    for (int nf = 0; nf < 2; nf++) {
      int row = qn * 32 + nf * 16 + l15;
#pragma unroll
      for (int kf = 0; kf < 2; kf++) {
        int pc = (kf * 4 + kq) ^ (row & 7);
        bb[nf][kf] = *(const u16x8*)(R + row * 64 + pc * 8);
      }
    }
  };

  f32x4 acc[4][4] = {};  // [mf][nfg], nfg = hb*2 + nf

  auto domfma = [&](u16x8 (&a)[4][2], u16x8 (&bb)[2][2], int hb) {
#pragma unroll
    for (int mf = 0; mf < 4; mf++)
#pragma unroll
      for (int nf = 0; nf < 2; nf++)
#pragma unroll
        for (int kf = 0; kf < 2; kf++)
          acc[mf][hb * 2 + nf] = __builtin_amdgcn_mfma_f32_16x16x32_bf16(
              __builtin_bit_cast(bf16x8, a[mf][kf]),
              __builtin_bit_cast(bf16x8, bb[nf][kf]), acc[mf][hb * 2 + nf], 0, 0, 0);
  };

  stage(0, 0); stage(0, 1); stage(0, 2); stage(1, 0); stage(1, 1);
  __asm__ __volatile__("s_waitcnt vmcnt(4)" ::: "memory");
  __builtin_amdgcn_s_barrier();

  for (int tt = 0; tt < NT; ++tt) {
    const unsigned short* Ar  = &Lg[tt & 1][0][0];
    const unsigned short* B0r = &Lg[tt & 1][1][0];
    const unsigned short* B1r = &Lg[tt & 1][2][0];
    u16x8 aA[4][2], bb[2][2];

    rdA(Ar, aA); rdB(B0r, bb);
    stage(tt + 1, 2);
    __builtin_amdgcn_s_barrier();
    __asm__ __volatile__("s_waitcnt lgkmcnt(0)" ::: "memory");
    __builtin_amdgcn_sched_barrier(0);
    __builtin_amdgcn_s_setprio(1);
    domfma(aA, bb, 0);
    __builtin_amdgcn_s_setprio(0);
    __builtin_amdgcn_s_barrier();

    rdB(B1r, bb);
    stage(tt + 2, 0); stage(tt + 2, 1);
    __builtin_amdgcn_s_barrier();
    __asm__ __volatile__("s_waitcnt lgkmcnt(0)" ::: "memory");
    __builtin_amdgcn_sched_barrier(0);
    __builtin_amdgcn_s_setprio(1);
    domfma(aA, bb, 1);
    __builtin_amdgcn_s_setprio(0);
    if (tt < NT - 2) {
      __asm__ __volatile__("s_waitcnt vmcnt(4)" ::: "memory");
    } else if (tt == NT - 2) {
      __asm__ __volatile__("s_waitcnt vmcnt(0)" ::: "memory");
    }
    __builtin_amdgcn_s_barrier();
  }

#pragma unroll
  for (int nfg = 0; nfg < 4; nfg++) {
    const int col = n0 + (nfg >> 1) * 128 + qn * 32 + (nfg & 1) * 16 + l15;
    float bv = b0[col];
#pragma unroll
    for (int mf = 0; mf < 4; mf++) {
      f32x4 v4 = acc[mf][nfg];
#pragma unroll
      for (int r = 0; r < 4; r++) {
        int row = m0 + qm * 64 + mf * 16 + kq * 4 + r;
        ((float*)out)[(size_t)row * N + col] = v4[r] + bv;
      }
    }
  }
}

// ---------------- Flash attention (causal), 32-row waves, in-register P --------------
// Swapped-operand (T12): per wave ONE 32-row q-tile, S^T = mfma(K, Q^T), softmax
// fully in-register (exp2 IN PLACE on sacc: -32 VGPR vs separate e[] arrays),
// P^T built via cvt_pk + permlane32_swap, PV: Y^T = V^T . P^T.
// R9: TLP fix. R1 (barrier-drain removal) and R8 (barrier-count halving) were
// both null, and all pipes idle at <40% -> the kernel is DEPENDENCY-LATENCY
// bound (QK->exp->pack->PV serial chain ~600 cyc/sub-tile) at only 2 waves/SIMD.
// Grid (64,16) = 1024 blocks = 4 blocks/CU = 4 waves/SIMD (2x the bubble-fill).
// KVBLK=64, LDS 32 KB, __launch_bounds__(256,4) caps VGPR at 128.
// jt = 4p+w; nit = 2p+2 block-uniform (max staged s-tile = 1984, in bounds);
// waves w0/w1 skip their inactive last sub-tile via the wave-uniform early-out.
// XCD: linear id = bh + 64p -> XCD = bh%8 (K/V L2-local, 8 bh x 512 KB = 4 MiB).
__global__ __launch_bounds__(256, 4) void attn_kernel(const unsigned short* __restrict__ Q,
                                                      const unsigned short* __restrict__ Km,
                                                      const unsigned short* __restrict__ Vt,
                                                      unsigned short* __restrict__ Y) {
  constexpr int T = 2048, D = 64;
  __shared__ __align__(16) unsigned short Ks[2][64 * 64];
  __shared__ __align__(16) unsigned short Vs[2][64 * 64];
  const int tid = threadIdx.x;
  const int lane = tid & 63, w = tid >> 6;
  const int l31 = lane & 31, half = lane >> 5;
  const int bh = blockIdx.x;  // XCD = bh % 8
  const int b = bh >> 4, h = bh & 15;
  const int p = blockIdx.y;   // 0..15
  const unsigned short* Qp = Q + (size_t)bh * T * D;
  const unsigned short* Kp = Km + (size_t)bh * T * D;
  const unsigned short* Vp = Vt + (size_t)bh * D * T;

  // staging constants (chunk-XOR swizzle; source pre-swizzled, LDS linear)
  const int bch0 = (w * 2) * 64, bch1 = (w * 2 + 1) * 64;
  const int ch0 = bch0 + lane, ch1 = bch1 + lane;
  const int row0 = ch0 >> 3, c0 = (ch0 & 7) ^ (row0 & 7);
  const int row1 = ch1 >> 3, c1 = (ch1 & 7) ^ (row1 & 7);

  const int jt = p * 4 + w;
  const int qt = jt * 32;
  const int nit = 2 * p + 2;  // block-uniform; covers ceil((qt+32)/64) for all w
  const int qg = qt + l31;    // this lane's q column

  bf16x8 aq[4];
#pragma unroll
  for (int kc = 0; kc < 4; kc++)
    aq[kc] = *(const bf16x8*)(Qp + (size_t)qg * D + kc * 16 + half * 8);
  // resolve aq now: keeps in-loop vmcnt brackets staging-only
  __asm__ __volatile__("" :: "v"(__builtin_bit_cast(f32x4, aq[0])),
                            "v"(__builtin_bit_cast(f32x4, aq[1])),
                            "v"(__builtin_bit_cast(f32x4, aq[2])),
                            "v"(__builtin_bit_cast(f32x4, aq[3])));

  f32x16 o0 = {}, o1 = {};  // Y^T accumulators, d-blocks 0/1
  float lsum = 0.f;

  // prologue: stage s-tile 0 into buffer 0
  gload_lds16(Kp + (size_t)row0 * 64 + c0 * 8, Ks[0] + bch0 * 8);
  gload_lds16(Kp + (size_t)row1 * 64 + c1 * 8, Ks[0] + bch1 * 8);
  gload_lds16(Vp + (size_t)row0 * T + c0 * 8, Vs[0] + bch0 * 8);
  gload_lds16(Vp + (size_t)row1 * T + c1 * 8, Vs[0] + bch1 * 8);

  int cur = 0;
  for (int it = 0; it < nit; ++it) {
    const int s0 = it * 64;
    if (it + 1 < nit) {  // block-uniform
      const int s1 = s0 + 64;
      unsigned short* kd = Ks[cur ^ 1];
      unsigned short* vd = Vs[cur ^ 1];
      gload_lds16(Kp + (size_t)(s1 + row0) * 64 + c0 * 8, kd + bch0 * 8);
      gload_lds16(Kp + (size_t)(s1 + row1) * 64 + c1 * 8, kd + bch1 * 8);
      gload_lds16(Vp + (size_t)row0 * T + s1 + c0 * 8, vd + bch0 * 8);
      gload_lds16(Vp + (size_t)row1 * T + s1 + c1 * 8, vd + bch1 * 8);
      __asm__ __volatile__("s_waitcnt vmcnt(4)" ::: "memory");
    } else {
      __asm__ __volatile__("s_waitcnt vmcnt(0)" ::: "memory");
    }
    __builtin_amdgcn_s_barrier();
    __builtin_amdgcn_sched_barrier(0);

    if (s0 <= qt + 31) {  // wave-uniform: skip fully-masked tiles
      const unsigned short* Kb_ = Ks[cur];
      const unsigned short* Vb_ = Vs[cur];

      // ---- S^T = K . Q^T : two 32-s blocks ----
      f32x16 sacc0 = {}, sacc1 = {};
#pragma unroll
      for (int kc = 0; kc < 4; kc++) {
        int kr0 = l31;
        int cc0 = (kc * 2 + half) ^ (kr0 & 7);
        u16x8 k0 = *(const u16x8*)(Kb_ + kr0 * 64 + cc0 * 8);
        sacc0 = __builtin_amdgcn_mfma_f32_32x32x16_bf16(
            __builtin_bit_cast(bf16x8, k0), aq[kc], sacc0, 0, 0, 0);
        int kr1 = 32 + l31;
        int cc1 = (kc * 2 + half) ^ (kr1 & 7);
        u16x8 k1 = *(const u16x8*)(Kb_ + kr1 * 64 + cc1 * 8);
        sacc1 = __builtin_amdgcn_mfma_f32_32x32x16_bf16(
            __builtin_bit_cast(bf16x8, k1), aq[kc], sacc1, 0, 0, 0);
      }

      // ---- exp2 + causal mask + denominator, IN PLACE on sacc ----
      const bool full = (s0 + 63) <= qt;
      if (full) {
#pragma unroll
        for (int r = 0; r < 16; r++) { sacc0[r] = fexp2(sacc0[r]); lsum += sacc0[r]; }
#pragma unroll
        for (int r = 0; r < 16; r++) { sacc1[r] = fexp2(sacc1[r]); lsum += sacc1[r]; }
      } else {
#pragma unroll
        for (int r = 0; r < 16; r++) {
          int sg = s0 + (r & 3) + 8 * (r >> 2) + 4 * half;
          float ex = fexp2(sacc0[r]);
          ex = (sg > qg) ? 0.f : ex;
          sacc0[r] = ex; lsum += ex;
        }
#pragma unroll
        for (int r = 0; r < 16; r++) {
          int sg = s0 + 32 + (r & 3) + 8 * (r >> 2) + 4 * half;
          float ex = fexp2(sacc1[r]);
          ex = (sg > qg) ? 0.f : ex;
          sacc1[r] = ex; lsum += ex;
        }
      }

      // ---- build P^T B-fragments in-register (T12: cvt_pk + permlane32_swap)
      bf16x8 pf[4];
      auto pack2 = [&](const f32x16& e_, int kbase) {
#pragma unroll
        for (int kl = 0; kl < 2; kl++) {
          int base = kl * 8;
          unsigned int a0 = cvtpk_bf16(e_[base + 0], e_[base + 1]);
          unsigned int b0v = cvtpk_bf16(e_[base + 4], e_[base + 5]);
          permswap32(a0, b0v);
          unsigned int a1 = cvtpk_bf16(e_[base + 2], e_[base + 3]);
          unsigned int b1v = cvtpk_bf16(e_[base + 6], e_[base + 7]);
          permswap32(a1, b1v);
          u32x4 t = {a0, a1, b0v, b1v};
          pf[kbase + kl] = __builtin_bit_cast(bf16x8, t);
        }
      };
      pack2(sacc0, 0);
      pack2(sacc1, 2);

      // ---- Y^T += V^T . P^T : two 32-d blocks ----
#pragma unroll
      for (int kc = 0; kc < 4; kc++) {
        int vr0 = l31;
        int cc0 = (kc * 2 + half) ^ (vr0 & 7);
        u16x8 v0 = *(const u16x8*)(Vb_ + vr0 * 64 + cc0 * 8);
        o0 = __builtin_amdgcn_mfma_f32_32x32x16_bf16(
            __builtin_bit_cast(bf16x8, v0), pf[kc], o0, 0, 0, 0);
        int vr1 = 32 + l31;
        int cc1 = (kc * 2 + half) ^ (vr1 & 7);
        u16x8 v1 = *(const u16x8*)(Vb_ + vr1 * 64 + cc1 * 8);
        o1 = __builtin_amdgcn_mfma_f32_32x32x16_bf16(
            __builtin_bit_cast(bf16x8, v1), pf[kc], o1, 0, 0, 0);
      }
    }

    __builtin_amdgcn_sched_barrier(0);
    __builtin_amdgcn_s_barrier();
    cur ^= 1;
  }

  float tot = lsum + __shfl_xor(lsum, 32);
  float inv = 1.f / tot;
  unsigned short* Yrow = Y + ((size_t)(b * T + qg)) * 1024 + h * 64;
#pragma unroll
  for (int rp = 0; rp < 8; rp++) {
    int r = rp * 2;
    int d = (r & 3) + 8 * (r >> 2) + 4 * half;
    *(unsigned int*)(Yrow + d)      = cvtpk_bf16(o0[r] * inv, o0[r + 1] * inv);
    *(unsigned int*)(Yrow + 32 + d) = cvtpk_bf16(o1[r] * inv, o1[r + 1] * inv);
  }
}

// ---------------- launch ----------------
extern "C" void kernel_launch(void* const* d_in, const int* in_sizes, int n_in,
                              void* d_out, int out_size, void* d_ws, size_t ws_size,
                              hipStream_t stream) {
  const float* x  = (const float*)d_in[0];
  const float* Wq = (const float*)d_in[1];
  const float* bq = (const float*)d_in[2];
  const float* Wk = (const float*)d_in[3];
  const float* bk = (const float*)d_in[4];
  const float* Wv = (const float*)d_in[5];
  const float* bv = (const float*)d_in[6];
  const float* Wp = (const float*)d_in[7];
  const float* bp = (const float*)d_in[8];

  char* ws = (char*)d_ws;
  unsigned short* xb  = (unsigned short*)(ws + 0);          // 16 MiB: x bf16; later Y
  unsigned short* wqb = (unsigned short*)(ws + 16777216);   // Wq,Wk,Wv contiguous = 3072x1024
  unsigned short* wkb = (unsigned short*)(ws + 18874368);
  unsigned short* wvb = (unsigned short*)(ws + 20971520);
  unsigned short* wpb = (unsigned short*)(ws + 23068672);
  unsigned short* Qb  = (unsigned short*)(ws + 25165824);   // Q,K contiguous, 16 MiB each
  unsigned short* Kb  = (unsigned short*)(ws + 41943040);
  unsigned short* Vtb = (unsigned short*)(ws + 58720256);   // Vt written by QKV epilogue
  unsigned short* Yb  = xb;  // x dead after fused QKV GEMM

  cvt_all<<<12288, 256, 0, stream>>>(x, Wq, Wk, Wv, Wp, xb, wqb, wkb, wvb, wpb);

  gemm128<0><<<dim3(64, 24), 256, 0, stream>>>(xb, wqb, bq, bk, bv, Qb, Vtb, 8192, 3072, 1024);

  attn_kernel<<<dim3(64, 16), 256, 0, stream>>>(Qb, Kb, Vtb, Yb);

  gemm8p<<<dim3(64, 4), 512, 0, stream>>>(Yb, wpb, bp, d_out, 8192, 1024, 1024);
}

// Round 11
// 227.153 us; speedup vs baseline: 1.0594x; 1.0594x over previous
//
#include <hip/hip_runtime.h>

typedef float f32x4 __attribute__((ext_vector_type(4)));
typedef float f32x16 __attribute__((ext_vector_type(16)));
typedef __bf16 bf16x8 __attribute__((ext_vector_type(8)));
typedef unsigned short u16x8 __attribute__((ext_vector_type(8)));
typedef unsigned int u32x4 __attribute__((ext_vector_type(4)));

#define SCQ 0.1803368801111183f  // 0.125 * log2(e): softmax in exp2 domain

__device__ inline unsigned short f2bf(float f) {
  unsigned int u = __builtin_bit_cast(unsigned int, f);
  u += 0x7FFFu + ((u >> 16) & 1u);
  return (unsigned short)(u >> 16);
}

__device__ inline float fexp2(float x) {
#if __has_builtin(__builtin_amdgcn_exp2f)
  return __builtin_amdgcn_exp2f(x);
#else
  return exp2f(x);
#endif
}

// pack two f32 -> one dword of 2 bf16 (lo = a, hi = b), RNE
__device__ inline unsigned int cvtpk_bf16(float a, float b) {
  unsigned int r;
  __asm__("v_cvt_pk_bf16_f32 %0, %1, %2" : "=v"(r) : "v"(a), "v"(b));
  return r;
}
// swap a's upper 32 lanes with b's lower 32 lanes (both modified)
__device__ inline void permswap32(unsigned int& a, unsigned int& b) {
  __asm__("v_permlane32_swap_b32 %0, %1" : "+v"(a), "+v"(b));
}

__device__ inline void gload_lds16(const unsigned short* g, unsigned short* l) {
  __builtin_amdgcn_global_load_lds(
      (const __attribute__((address_space(1))) unsigned int*)g,
      (__attribute__((address_space(3))) unsigned int*)l, 16, 0, 0);
}

// ---------------- fp32 -> bf16 conversion (x + 4 weight matrices, one launch) ----
__global__ void cvt_all(const float* __restrict__ x,
                        const float* __restrict__ wq, const float* __restrict__ wk,
                        const float* __restrict__ wv, const float* __restrict__ wp,
                        unsigned short* __restrict__ xb,
                        unsigned short* __restrict__ oq, unsigned short* __restrict__ ok,
                        unsigned short* __restrict__ ov, unsigned short* __restrict__ op_) {
  int gid = blockIdx.x;
  const float* src;
  unsigned short* dst;
  int i;
  if (gid < 8192) {
    src = x; dst = xb;
    i = (gid * 256 + threadIdx.x) * 4;
  } else {
    int g = gid - 8192;
    int m = g >> 10;
    src = (m == 0) ? wq : (m == 1) ? wk : (m == 2) ? wv : wp;
    dst = (m == 0) ? oq : (m == 1) ? ok : (m == 2) ? ov : op_;
    i = ((g & 1023) * 256 + threadIdx.x) * 4;
  }
  float4 f = *(const float4*)(src + i);
  ushort4 o;
  o.x = f2bf(f.x); o.y = f2bf(f.y); o.z = f2bf(f.z); o.w = f2bf(f.w);
  *(ushort4*)(dst + i) = o;
}

// ---------------- GEMM 128x128 (m97 structure), LDS-retiled epilogues ----------
// out[m][n] = sum_k A[m][k]*Bt[n][k] + bias[n]. 256 thr = 4 waves, 64x64/wave,
// 2x2 of 32x32x16 MFMA, BK=64, global_load_lds w16, chunk-XOR swizzle.
// MODE 0 (fused QKV, N=3072): which=col>>10 -> {Q,K,V}.
//   Q/K (n0<2048): R11 — the old per-element scatter stored 64x2B per thread in
//     64B segments (1/8 coalescing) and sat on each block's critical tail.
//     Each block owns a CONTIGUOUS 16KB region per head ([t0..t0+127]x[64d]),
//     so: acc -> LDS [t][d] tile (2-way-free u16 writes) -> two 16KB head-chunk
//     copies with u16x8 stores (1KB/wave-instr, fully coalesced).
//   V (n0>=2048): acc -> XOR-swizzled [d][t] LDS tile -> vt[bh][d][t]
//     transposed, coalesced (replaces the transpose_v kernel).
// MODE 1: fp32 row-major MxN with bias b0.
template <int MODE>
__global__ __launch_bounds__(256) void gemm128(const unsigned short* __restrict__ A,
                                               const unsigned short* __restrict__ Bt,
                                               const float* __restrict__ b0,
                                               const float* __restrict__ b1,
                                               const float* __restrict__ b2,
                                               void* __restrict__ out,
                                               unsigned short* __restrict__ vt,
                                               int M, int N, int K) {
  __shared__ __align__(16) unsigned short Sh[2][128 * 64];
  unsigned short* As = Sh[0];
  unsigned short* Bs = Sh[1];
  const int tid = threadIdx.x;
  const int lane = tid & 63, w = tid >> 6;
  const int l31 = lane & 31, half = lane >> 5;
  const int wm = w & 1, wn = w >> 1;
  const int m0 = blockIdx.x * 128, n0 = blockIdx.y * 128;

  f32x16 acc[2][2] = {};

  for (int kb = 0; kb < K; kb += 64) {
#pragma unroll
    for (int j = 0; j < 4; j++) {
      int ch = j * 256 + w * 64 + lane;
      int row = ch >> 3, pc = ch & 7;
      int c = pc ^ (row & 7);
      gload_lds16(A + (size_t)(m0 + row) * K + kb + c * 8, As + (size_t)(j * 256 + w * 64) * 8);
      gload_lds16(Bt + (size_t)(n0 + row) * K + kb + c * 8, Bs + (size_t)(j * 256 + w * 64) * 8);
    }
    __syncthreads();
#pragma unroll
    for (int ks = 0; ks < 64; ks += 16) {
      bf16x8 af[2], bfr[2];
#pragma unroll
      for (int at = 0; at < 2; at++) {
        int row = wm * 64 + at * 32 + l31;
        int pc = ((ks >> 3) + half) ^ (row & 7);
        af[at] = *(const bf16x8*)(As + row * 64 + pc * 8);
      }
#pragma unroll
      for (int nt = 0; nt < 2; nt++) {
        int row = wn * 64 + nt * 32 + l31;
        int pc = ((ks >> 3) + half) ^ (row & 7);
        bfr[nt] = *(const bf16x8*)(Bs + row * 64 + pc * 8);
      }
#pragma unroll
      for (int at = 0; at < 2; at++)
#pragma unroll
        for (int nt = 0; nt < 2; nt++)
          acc[at][nt] = __builtin_amdgcn_mfma_f32_32x32x16_bf16(af[at], bfr[nt], acc[at][nt], 0, 0, 0);
    }
    __syncthreads();
  }

  if (MODE == 0) {
    const int bb = m0 >> 11, t0 = m0 & 2047;
    if (n0 >= 2048) {
      // ---- V: LDS transpose + coalesced Vt store ----
      unsigned short* Lt = &Sh[0][0];  // 128 x 128 u16 = 32 KB (staging LDS, dead)
#pragma unroll
      for (int at = 0; at < 2; at++)
#pragma unroll
        for (int nt = 0; nt < 2; nt++) {
          int d = wn * 64 + nt * 32 + l31;          // d_local in [0,128)
          float bv = b2[(n0 & 1023) + d];
          int swz = (d & 31) << 2;                  // bank-spread XOR, bijective in t
#pragma unroll
          for (int reg = 0; reg < 16; reg++) {
            int t = wm * 64 + at * 32 + (reg & 3) + 8 * (reg >> 2) + 4 * half;
            Lt[d * 128 + (t ^ swz)] = f2bf(acc[at][nt][reg] + bv);
          }
        }
      __syncthreads();
#pragma unroll
      for (int i = 0; i < 16; i++) {
        int d = (tid >> 5) + i * 8;
        int tb = (tid & 31) * 4;
        ushort4 val = *(const ushort4*)&Lt[d * 128 + (tb ^ ((d & 31) << 2))];
        int h = ((n0 & 1023) + d) >> 6;
        *(ushort4*)(vt + ((size_t)((bb * 16 + h) * 64 + (d & 63))) * 2048 + t0 + tb) = val;
      }
    } else {
      // ---- Q/K: LDS re-tile [t][d] + coalesced 16 KB head-chunk stores (R11) ----
      unsigned short* Lt = &Sh[0][0];  // 128 x 128 u16 = 32 KB
      const int which = n0 >> 10;
      const float sc = (which == 0) ? SCQ : 1.f;
      const float* bp = (which == 0) ? b0 : b1;
#pragma unroll
      for (int at = 0; at < 2; at++)
#pragma unroll
        for (int nt = 0; nt < 2; nt++) {
          int d = wn * 64 + nt * 32 + l31;          // 0..127
          float bv = bp[(n0 & 1023) + d];
#pragma unroll
          for (int reg = 0; reg < 16; reg++) {
            int t = wm * 64 + at * 32 + (reg & 3) + 8 * (reg >> 2) + 4 * half;
            Lt[t * 128 + d] = f2bf((acc[at][nt][reg] + bv) * sc);
          }
        }
      __syncthreads();
#pragma unroll
      for (int hh2 = 0; hh2 < 2; hh2++) {
        const int cl = (n0 & 1023) + hh2 * 64;
        const int hh = cl >> 6;
        unsigned short* chunk = (unsigned short*)out + (size_t)which * 8388608 +
                                ((size_t)((bb * 16 + hh) * 2048 + t0)) * 64;
#pragma unroll
        for (int ps = 0; ps < 4; ps++) {
          int g = ps * 2048 + tid * 8;              // t_local = g>>6, d_local = g&63
          u16x8 v = *(const u16x8*)&Lt[(g >> 6) * 128 + hh2 * 64 + (g & 63)];
          *(u16x8*)(chunk + g) = v;                 // 16B/lane, fully coalesced
        }
      }
    }
    return;
  }

#pragma unroll
  for (int at = 0; at < 2; at++)
#pragma unroll
    for (int nt = 0; nt < 2; nt++) {
      int col = n0 + wn * 64 + nt * 32 + l31;
      float bv = b0[col];
#pragma unroll
      for (int reg = 0; reg < 16; reg++) {
        int row = m0 + wm * 64 + at * 32 + (reg & 3) + 8 * (reg >> 2) + 4 * half;
        ((float*)out)[(size_t)row * N + col] = acc[at][nt][reg] + bv;
      }
    }
}

// ---------------- GEMM 128x256, counted-vmcnt schedule (proj) ----------------
__global__ __launch_bounds__(512, 2) void gemm8p(const unsigned short* __restrict__ A,
                                                 const unsigned short* __restrict__ Bt,
                                                 const float* __restrict__ b0,
                                                 void* __restrict__ out,
                                                 int M, int N, int K) {
  __shared__ __align__(16) unsigned short Lg[2][3][128 * 64];
  const int tid = threadIdx.x;
  const int lane = tid & 63, w = tid >> 6;
  const int qm = w >> 2, qn = w & 3;       // wave position: 2M x 4N
  const int l15 = lane & 15, kq = lane >> 4;
  const int m0 = blockIdx.x * 128, n0 = blockIdx.y * 256;
  const int NT = K >> 6;

  const int row0 = tid >> 3, c0 = (tid & 7) ^ (row0 & 7);
  const int row1 = row0 + 64, c1 = (tid & 7) ^ (row1 & 7);

  auto stage = [&](int tt, int h) {
    if (tt < NT) {
      const unsigned short* s_ = (h == 0) ? A : Bt;
      const int rbase = (h == 0) ? m0 : (h == 1 ? n0 : n0 + 128);
      unsigned short* d = &Lg[tt & 1][h][0];
      gload_lds16(s_ + (size_t)(rbase + row0) * K + tt * 64 + c0 * 8, d + (size_t)tid * 8);
      gload_lds16(s_ + (size_t)(rbase + row1) * K + tt * 64 + c1 * 8, d + (size_t)(tid + 512) * 8);
    }
  };

  auto rdA = [&](const unsigned short* R, u16x8 (&a)[4][2]) {
#pragma unroll
    for (int mf = 0; mf < 4; mf++) {
      int row = qm * 64 + mf * 16 + l15;
#pragma unroll
      for (int kf = 0; kf < 2; kf++) {
        int pc = (kf * 4 + kq) ^ (row & 7);
        a[mf][kf] = *(const u16x8*)(R + row * 64 + pc * 8);
      }
    }
  };
  auto rdB = [&](const unsigned short* R, u16x8 (&bb)[2][2]) {
#pragma unroll
    for (int nf = 0; nf < 2; nf++) {
      int row = qn * 32 + nf * 16 + l15;
#pragma unroll
      for (int kf = 0; kf < 2; kf++) {
        int pc = (kf * 4 + kq) ^ (row & 7);
        bb[nf][kf] = *(const u16x8*)(R + row * 64 + pc * 8);
      }
    }
  };

  f32x4 acc[4][4] = {};  // [mf][nfg], nfg = hb*2 + nf

  auto domfma = [&](u16x8 (&a)[4][2], u16x8 (&bb)[2][2], int hb) {
#pragma unroll
    for (int mf = 0; mf < 4; mf++)
#pragma unroll
      for (int nf = 0; nf < 2; nf++)
#pragma unroll
        for (int kf = 0; kf < 2; kf++)
          acc[mf][hb * 2 + nf] = __builtin_amdgcn_mfma_f32_16x16x32_bf16(
              __builtin_bit_cast(bf16x8, a[mf][kf]),
              __builtin_bit_cast(bf16x8, bb[nf][kf]), acc[mf][hb * 2 + nf], 0, 0, 0);
  };

  stage(0, 0); stage(0, 1); stage(0, 2); stage(1, 0); stage(1, 1);
  __asm__ __volatile__("s_waitcnt vmcnt(4)" ::: "memory");
  __builtin_amdgcn_s_barrier();

  for (int tt = 0; tt < NT; ++tt) {
    const unsigned short* Ar  = &Lg[tt & 1][0][0];
    const unsigned short* B0r = &Lg[tt & 1][1][0];
    const unsigned short* B1r = &Lg[tt & 1][2][0];
    u16x8 aA[4][2], bb[2][2];

    rdA(Ar, aA); rdB(B0r, bb);
    stage(tt + 1, 2);
    __builtin_amdgcn_s_barrier();
    __asm__ __volatile__("s_waitcnt lgkmcnt(0)" ::: "memory");
    __builtin_amdgcn_sched_barrier(0);
    __builtin_amdgcn_s_setprio(1);
    domfma(aA, bb, 0);
    __builtin_amdgcn_s_setprio(0);
    __builtin_amdgcn_s_barrier();

    rdB(B1r, bb);
    stage(tt + 2, 0); stage(tt + 2, 1);
    __builtin_amdgcn_s_barrier();
    __asm__ __volatile__("s_waitcnt lgkmcnt(0)" ::: "memory");
    __builtin_amdgcn_sched_barrier(0);
    __builtin_amdgcn_s_setprio(1);
    domfma(aA, bb, 1);
    __builtin_amdgcn_s_setprio(0);
    if (tt < NT - 2) {
      __asm__ __volatile__("s_waitcnt vmcnt(4)" ::: "memory");
    } else if (tt == NT - 2) {
      __asm__ __volatile__("s_waitcnt vmcnt(0)" ::: "memory");
    }
    __builtin_amdgcn_s_barrier();
  }

#pragma unroll
  for (int nfg = 0; nfg < 4; nfg++) {
    const int col = n0 + (nfg >> 1) * 128 + qn * 32 + (nfg & 1) * 16 + l15;
    float bv = b0[col];
#pragma unroll
    for (int mf = 0; mf < 4; mf++) {
      f32x4 v4 = acc[mf][nfg];
#pragma unroll
      for (int r = 0; r < 4; r++) {
        int row = m0 + qm * 64 + mf * 16 + kq * 4 + r;
        ((float*)out)[(size_t)row * N + col] = v4[r] + bv;
      }
    }
  }
}

// ---------------- Flash attention (causal), 32-row waves, in-register P --------------
// Swapped-operand (T12); KVBLK = 128 processed as 2x64 sub-tiles reusing the
// same sacc registers (R8 variant — best measured). 2-phase q-tile pairing,
// grid (64,8), LDS 64 KB (2 blocks/CU), counted vmcnt(8) one tile ahead.
// Iteration counts block-uniform: phase0 nit = p+1, phase1 nit = 16-p.
__global__ __launch_bounds__(256, 2) void attn_kernel(const unsigned short* __restrict__ Q,
                                                      const unsigned short* __restrict__ Km,
                                                      const unsigned short* __restrict__ Vt,
                                                      unsigned short* __restrict__ Y) {
  constexpr int T = 2048, D = 64;
  __shared__ __align__(16) unsigned short Ks[2][128 * 64];  // [s 0..127][d 0..63]
  __shared__ __align__(16) unsigned short Vs[2][64 * 128];  // [d 0..63][s 0..127]
  const int tid = threadIdx.x;
  const int lane = tid & 63, w = tid >> 6;
  const int l31 = lane & 31, half = lane >> 5;
  const int bh = blockIdx.x;  // XCD = bh % 8
  const int b = bh >> 4, h = bh & 15;
  const int p = blockIdx.y;   // 0..7
  const unsigned short* Qp = Q + (size_t)bh * T * D;
  const unsigned short* Kp = Km + (size_t)bh * T * D;
  const unsigned short* Vp = Vt + (size_t)bh * D * T;

  int krow[4], kc_[4], vd_[4], vc_[4];
#pragma unroll
  for (int q = 0; q < 4; q++) {
    int ch = w * 256 + q * 64 + lane;
    krow[q] = ch >> 3; kc_[q] = (ch & 7) ^ (krow[q] & 7);
    vd_[q] = ch >> 4;  vc_[q] = (ch & 15) ^ (vd_[q] & 7);
  }
  const int chb = w * 256;

  for (int phase = 0; phase < 2; ++phase) {
    const int jt = phase ? (63 - (p * 4 + w)) : (p * 4 + w);
    const int qt = jt * 32;
    const int nit = phase ? (16 - p) : (p + 1);  // block-uniform (128-wide tiles)
    const int qg = qt + l31;  // this lane's q column

    bf16x8 aq[4];
#pragma unroll
    for (int kc = 0; kc < 4; kc++)
      aq[kc] = *(const bf16x8*)(Qp + (size_t)qg * D + kc * 16 + half * 8);
    __asm__ __volatile__("" :: "v"(__builtin_bit_cast(f32x4, aq[0])),
                              "v"(__builtin_bit_cast(f32x4, aq[1])),
                              "v"(__builtin_bit_cast(f32x4, aq[2])),
                              "v"(__builtin_bit_cast(f32x4, aq[3])));

    f32x16 o0 = {}, o1 = {};  // Y^T accumulators, d-blocks 0/1
    float lsum = 0.f;

    // prologue: stage s-tile 0 (128 wide) into buffer 0
#pragma unroll
    for (int q = 0; q < 4; q++) {
      gload_lds16(Kp + (size_t)krow[q] * 64 + kc_[q] * 8, Ks[0] + (size_t)(chb + q * 64) * 8);
      gload_lds16(Vp + (size_t)vd_[q] * T + vc_[q] * 8, Vs[0] + (size_t)(chb + q * 64) * 8);
    }

    int cur = 0;
    for (int it = 0; it < nit; ++it) {
      const int s0 = it * 128;
      if (it + 1 < nit) {  // block-uniform
        const int s1 = s0 + 128;
        unsigned short* kd = Ks[cur ^ 1];
        unsigned short* vd = Vs[cur ^ 1];
#pragma unroll
        for (int q = 0; q < 4; q++) {
          gload_lds16(Kp + (size_t)(s1 + krow[q]) * 64 + kc_[q] * 8, kd + (size_t)(chb + q * 64) * 8);
          gload_lds16(Vp + (size_t)vd_[q] * T + s1 + vc_[q] * 8, vd + (size_t)(chb + q * 64) * 8);
        }
        __asm__ __volatile__("s_waitcnt vmcnt(8)" ::: "memory");
      } else {
        __asm__ __volatile__("s_waitcnt vmcnt(0)" ::: "memory");
      }
      __builtin_amdgcn_s_barrier();
      __builtin_amdgcn_sched_barrier(0);

      const unsigned short* Kb_ = Ks[cur];
      const unsigned short* Vb_ = Vs[cur];

#pragma unroll
      for (int sub = 0; sub < 2; sub++) {
        const int s0s = s0 + sub * 64;
        if (s0s <= qt + 31) {  // wave-uniform: skip fully-masked sub-tiles
          f32x16 sacc0 = {}, sacc1 = {};
#pragma unroll
          for (int kc = 0; kc < 4; kc++) {
            int kr0 = sub * 64 + l31;
            int cc0 = (kc * 2 + half) ^ (kr0 & 7);
            u16x8 k0 = *(const u16x8*)(Kb_ + kr0 * 64 + cc0 * 8);
            sacc0 = __builtin_amdgcn_mfma_f32_32x32x16_bf16(
                __builtin_bit_cast(bf16x8, k0), aq[kc], sacc0, 0, 0, 0);
            int kr1 = sub * 64 + 32 + l31;
            int cc1 = (kc * 2 + half) ^ (kr1 & 7);
            u16x8 k1 = *(const u16x8*)(Kb_ + kr1 * 64 + cc1 * 8);
            sacc1 = __builtin_amdgcn_mfma_f32_32x32x16_bf16(
                __builtin_bit_cast(bf16x8, k1), aq[kc], sacc1, 0, 0, 0);
          }

          const bool full = (s0s + 63) <= qt;
          float e0_[16], e1_[16];
          if (full) {
#pragma unroll
            for (int r = 0; r < 16; r++) { e0_[r] = fexp2(sacc0[r]); lsum += e0_[r]; }
#pragma unroll
            for (int r = 0; r < 16; r++) { e1_[r] = fexp2(sacc1[r]); lsum += e1_[r]; }
          } else {
#pragma unroll
            for (int r = 0; r < 16; r++) {
              int sg = s0s + (r & 3) + 8 * (r >> 2) + 4 * half;
              float ex = fexp2(sacc0[r]);
              ex = (sg > qg) ? 0.f : ex;
              e0_[r] = ex; lsum += ex;
            }
#pragma unroll
            for (int r = 0; r < 16; r++) {
              int sg = s0s + 32 + (r & 3) + 8 * (r >> 2) + 4 * half;
              float ex = fexp2(sacc1[r]);
              ex = (sg > qg) ? 0.f : ex;
              e1_[r] = ex; lsum += ex;
            }
          }

          bf16x8 pf[4];
          auto pack2 = [&](const float* e_, int kbase) {
#pragma unroll
            for (int kl = 0; kl < 2; kl++) {
              int base = kl * 8;
              unsigned int a0 = cvtpk_bf16(e_[base + 0], e_[base + 1]);
              unsigned int b0v = cvtpk_bf16(e_[base + 4], e_[base + 5]);
              permswap32(a0, b0v);
              unsigned int a1 = cvtpk_bf16(e_[base + 2], e_[base + 3]);
              unsigned int b1v = cvtpk_bf16(e_[base + 6], e_[base + 7]);
              permswap32(a1, b1v);
              u32x4 t = {a0, a1, b0v, b1v};
              pf[kbase + kl] = __builtin_bit_cast(bf16x8, t);
            }
          };
          pack2(e0_, 0);
          pack2(e1_, 2);

#pragma unroll
          for (int kc = 0; kc < 4; kc++) {
            int sch = sub * 8 + kc * 2 + half;
            int vr0 = l31;
            int cc0 = sch ^ (vr0 & 7);
            u16x8 v0 = *(const u16x8*)(Vb_ + vr0 * 128 + cc0 * 8);
            o0 = __builtin_amdgcn_mfma_f32_32x32x16_bf16(
                __builtin_bit_cast(bf16x8, v0), pf[kc], o0, 0, 0, 0);
            int vr1 = 32 + l31;
            int cc1 = sch ^ (vr1 & 7);
            u16x8 v1 = *(const u16x8*)(Vb_ + vr1 * 128 + cc1 * 8);
            o1 = __builtin_amdgcn_mfma_f32_32x32x16_bf16(
                __builtin_bit_cast(bf16x8, v1), pf[kc], o1, 0, 0, 0);
          }
        }
      }

      __builtin_amdgcn_sched_barrier(0);
      __builtin_amdgcn_s_barrier();
      cur ^= 1;
    }

    float tot = lsum + __shfl_xor(lsum, 32);
    float inv = 1.f / tot;
    unsigned short* Yrow = Y + ((size_t)(b * T + qg)) * 1024 + h * 64;
#pragma unroll
    for (int rp = 0; rp < 8; rp++) {
      int r = rp * 2;
      int d = (r & 3) + 8 * (r >> 2) + 4 * half;
      *(unsigned int*)(Yrow + d)      = cvtpk_bf16(o0[r] * inv, o0[r + 1] * inv);
      *(unsigned int*)(Yrow + 32 + d) = cvtpk_bf16(o1[r] * inv, o1[r + 1] * inv);
    }
  }
}

// ---------------- launch ----------------
extern "C" void kernel_launch(void* const* d_in, const int* in_sizes, int n_in,
                              void* d_out, int out_size, void* d_ws, size_t ws_size,
                              hipStream_t stream) {
  const float* x  = (const float*)d_in[0];
  const float* Wq = (const float*)d_in[1];
  const float* bq = (const float*)d_in[2];
  const float* Wk = (const float*)d_in[3];
  const float* bk = (const float*)d_in[4];
  const float* Wv = (const float*)d_in[5];
  const float* bv = (const float*)d_in[6];
  const float* Wp = (const float*)d_in[7];
  const float* bp = (const float*)d_in[8];

  char* ws = (char*)d_ws;
  unsigned short* xb  = (unsigned short*)(ws + 0);          // 16 MiB: x bf16; later Y
  unsigned short* wqb = (unsigned short*)(ws + 16777216);   // Wq,Wk,Wv contiguous = 3072x1024
  unsigned short* wkb = (unsigned short*)(ws + 18874368);
  unsigned short* wvb = (unsigned short*)(ws + 20971520);
  unsigned short* wpb = (unsigned short*)(ws + 23068672);
  unsigned short* Qb  = (unsigned short*)(ws + 25165824);   // Q,K contiguous, 16 MiB each
  unsigned short* Kb  = (unsigned short*)(ws + 41943040);
  unsigned short* Vtb = (unsigned short*)(ws + 58720256);   // Vt written by QKV epilogue
  unsigned short* Yb  = xb;  // x dead after fused QKV GEMM

  cvt_all<<<12288, 256, 0, stream>>>(x, Wq, Wk, Wv, Wp, xb, wqb, wkb, wvb, wpb);

  gemm128<0><<<dim3(64, 24), 256, 0, stream>>>(xb, wqb, bq, bk, bv, Qb, Vtb, 8192, 3072, 1024);

  attn_kernel<<<dim3(64, 8), 256, 0, stream>>>(Qb, Kb, Vtb, Yb);

  gemm8p<<<dim3(64, 4), 512, 0, stream>>>(Yb, wpb, bp, d_out, 8192, 1024, 1024);
}